// Round 7
// baseline (442.141 us; speedup 1.0000x reference)
//
#include <hip/hip_runtime.h>
#include <math.h>

#define B_ 4
#define S_ 2048
#define D_ 1024
#define T_ 5
#define H_ 8
#define HD_ 128
#define M_ (B_*S_)   // 8192 rows total

typedef __bf16 bf16x8 __attribute__((ext_vector_type(8)));
typedef float  f32x4  __attribute__((ext_vector_type(4)));

__device__ __forceinline__ float bf2f(unsigned short u) {
    union { unsigned int i; float f; } c; c.i = ((unsigned int)u) << 16; return c.f;
}
__device__ __forceinline__ unsigned short f2bf(float f) {
    union { float f; unsigned int i; } c; c.f = f;
    unsigned int u = c.i;
    u += 0x7fffu + ((u >> 16) & 1u);   // RNE
    return (unsigned short)(u >> 16);
}

__device__ __forceinline__ void gll16(const void* g, void* l) {
    // global->LDS DMA, 16B per lane; LDS dest = wave-uniform base + lane*16
    __builtin_amdgcn_global_load_lds(
        (const __attribute__((address_space(1))) void*)g,
        (__attribute__((address_space(3))) void*)l, 16, 0, 0);
}

// ---------------------------------------------------------------------------
// Kernel 0: fp32 -> bf16 elementwise (weight conversion). n % 1024 == 0.
// ---------------------------------------------------------------------------
__global__ __launch_bounds__(256) void f2bf_kernel(
    const float* __restrict__ src, unsigned short* __restrict__ dst)
{
    int i = (blockIdx.x * 256 + threadIdx.x) * 4;
    float4 v = *(const float4*)(src + i);
    ushort4 o;
    o.x = f2bf(v.x); o.y = f2bf(v.y); o.z = f2bf(v.z); o.w = f2bf(v.w);
    *(ushort4*)(dst + i) = o;
}

// ---------------------------------------------------------------------------
// Kernel 1: per-token indexed LayerNorm + decay -> bf16 out.
// ---------------------------------------------------------------------------
__global__ __launch_bounds__(256) void ln_kernel(
    const float* __restrict__ x, const int* __restrict__ ts,
    const float* __restrict__ gamma, const float* __restrict__ beta,
    const float* __restrict__ decay, unsigned short* __restrict__ out)
{
    int row = blockIdx.x;
    int tid = threadIdx.x;
    float4 v = ((const float4*)(x + (size_t)row * D_))[tid];
    float s  = v.x + v.y + v.z + v.w;
    float s2 = v.x*v.x + v.y*v.y + v.z*v.z + v.w*v.w;
    #pragma unroll
    for (int off = 32; off; off >>= 1) {
        s  += __shfl_down(s,  off);
        s2 += __shfl_down(s2, off);
    }
    __shared__ float ps[4], ps2[4];
    if ((tid & 63) == 0) { ps[tid >> 6] = s; ps2[tid >> 6] = s2; }
    __syncthreads();
    float tot  = ps[0]  + ps[1]  + ps[2]  + ps[3];
    float tot2 = ps2[0] + ps2[1] + ps2[2] + ps2[3];
    float mu   = tot  * (1.0f / D_);
    float var  = tot2 * (1.0f / D_) - mu * mu;
    float rstd = rsqrtf(var + 1e-5f);

    int t  = ts[row];
    int tc = min(max(t, 0), T_ - 1);
    float4 g = ((const float4*)(gamma + (size_t)tc * D_))[tid];
    float4 b = ((const float4*)(beta  + (size_t)tc * D_))[tid];
    float dec = decay[tc];

    float4 o;
    o.x = ((v.x - mu) * rstd * g.x + b.x) * dec;
    o.y = ((v.y - mu) * rstd * g.y + b.y) * dec;
    o.z = ((v.z - mu) * rstd * g.z + b.z) * dec;
    o.w = ((v.w - mu) * rstd * g.w + b.w) * dec;
    if (t >= T_) o = v;
    ushort4 ob;
    ob.x = f2bf(o.x); ob.y = f2bf(o.y); ob.z = f2bf(o.z); ob.w = f2bf(o.w);
    ((ushort4*)(out + (size_t)row * D_))[tid] = ob;
}

// ---------------------------------------------------------------------------
// MFMA GEMM: C[i,j] = Res[i,j] + sum_k A[i,k]*Wt[j,k] + bias[j]
// 128x128 tile, BK=32, 4 waves (each 64x64), 16x16x32 bf16 MFMA.
// ---------------------------------------------------------------------------
__global__ __launch_bounds__(256) void gemm_mfma(
    const unsigned short* __restrict__ A,
    const unsigned short* __restrict__ Wt,
    const float* __restrict__ bias,
    const float* __restrict__ ResF,
    const unsigned short* __restrict__ ResB,
    float* __restrict__ Cf,
    unsigned short* __restrict__ Cb,
    int M, int N, int K)
{
    __shared__ __align__(16) unsigned short As[128 * 32];
    __shared__ __align__(16) unsigned short Bs[128 * 32];
    int tid  = threadIdx.x;
    int w    = tid >> 6, lane = tid & 63;
    int lm   = lane & 15, quad = lane >> 4;
    int wm   = w & 1,  wn   = w >> 1;
    int i0 = blockIdx.y * 128, j0 = blockIdx.x * 128;

    f32x4 acc[4][4];
    #pragma unroll
    for (int mt = 0; mt < 4; ++mt)
        #pragma unroll
        for (int nt = 0; nt < 4; ++nt)
            acc[mt][nt] = (f32x4){0.f, 0.f, 0.f, 0.f};

    int c0 = w * 128 + lane;
    int r0 = c0 >> 2,   k80 = (c0 & 3) * 8;
    int c1 = c0 + 64;
    int r1 = c1 >> 2,   k81 = (c1 & 3) * 8;

    for (int kt = 0; kt < K; kt += 32) {
        __syncthreads();
        gll16(A  + (size_t)(i0 + r0) * K + kt + k80, As + (size_t)(w * 128 + 0 ) * 8);
        gll16(A  + (size_t)(i0 + r1) * K + kt + k81, As + (size_t)(w * 128 + 64) * 8);
        gll16(Wt + (size_t)(j0 + r0) * K + kt + k80, Bs + (size_t)(w * 128 + 0 ) * 8);
        gll16(Wt + (size_t)(j0 + r1) * K + kt + k81, Bs + (size_t)(w * 128 + 64) * 8);
        __syncthreads();

        bf16x8 af[4], bfr[4];
        #pragma unroll
        for (int mt = 0; mt < 4; ++mt)
            af[mt] = *(const bf16x8*)&As[(wm * 64 + mt * 16 + lm) * 32 + quad * 8];
        #pragma unroll
        for (int nt = 0; nt < 4; ++nt)
            bfr[nt] = *(const bf16x8*)&Bs[(wn * 64 + nt * 16 + lm) * 32 + quad * 8];
        #pragma unroll
        for (int mt = 0; mt < 4; ++mt)
            #pragma unroll
            for (int nt = 0; nt < 4; ++nt)
                acc[mt][nt] = __builtin_amdgcn_mfma_f32_16x16x32_bf16(
                    af[mt], bfr[nt], acc[mt][nt], 0, 0, 0);
    }

    #pragma unroll
    for (int nt = 0; nt < 4; ++nt) {
        int j = j0 + wn * 64 + nt * 16 + lm;
        float bj = bias[j];
        #pragma unroll
        for (int mt = 0; mt < 4; ++mt) {
            #pragma unroll
            for (int r = 0; r < 4; ++r) {
                int i = i0 + wm * 64 + mt * 16 + quad * 4 + r;
                size_t off = (size_t)i * N + j;
                float v = acc[mt][nt][r] + bj;
                if (ResF) v += ResF[off];
                else if (ResB) v += bf2f(ResB[off]);
                if (Cf) Cf[off] = v;
                if (Cb) Cb[off] = f2bf(v);
            }
        }
    }
}

// ---------------------------------------------------------------------------
// Kernel 3b: transpose V part of qkv into vt[b][dcol][s] (bf16).
// ---------------------------------------------------------------------------
__global__ __launch_bounds__(256) void transpose_v(
    const unsigned short* __restrict__ qkv, unsigned short* __restrict__ vt)
{
    __shared__ unsigned short Ts[64][72];
    int t = threadIdx.x;
    int s0 = blockIdx.x * 64, c0 = blockIdx.y * 64, b = blockIdx.z;
    int r  = t >> 2, cg = (t & 3) * 16;
    const unsigned short* src =
        qkv + (size_t)(b * S_ + s0 + r) * (3 * D_) + 2 * D_ + c0 + cg;
    *(bf16x8*)&Ts[r][cg]     = *(const bf16x8*)(src);
    *(bf16x8*)&Ts[r][cg + 8] = *(const bf16x8*)(src + 8);
    __syncthreads();
    int dd = t >> 2, sg = (t & 3) * 16;
    unsigned short tmp[16];
    #pragma unroll
    for (int j = 0; j < 16; ++j) tmp[j] = Ts[sg + j][dd];
    unsigned short* dst = vt + ((size_t)b * D_ + c0 + dd) * S_ + s0 + sg;
    *(bf16x8*)dst       = *(bf16x8*)&tmp[0];
    *(bf16x8*)(dst + 8) = *(bf16x8*)&tmp[8];
}

// ---------------------------------------------------------------------------
// Kernel 4: MFMA flash attention, fixed-max softmax (logits bounded).
// q-tile 64 (4 waves x 16 q-rows), kv-tile 64, grid 1024 blocks 1D with
// XCD swizzle: bh = blk & 31 (same bh -> same blk%8 -> same XCD L2),
// qt = blk >> 5. LDS 44KB -> 3 blocks/CU (12 waves/CU).
// ---------------------------------------------------------------------------
__global__ __launch_bounds__(256, 3) void flash_mfma(
    const unsigned short* __restrict__ qkv,
    const unsigned short* __restrict__ vt,
    unsigned short* __restrict__ ctx)
{
    __shared__ unsigned short Ks [64][136];   // K tile [kv][d], +8 pad
    __shared__ unsigned short Vts[128][72];   // V^T tile [d][kv], +8 pad
    __shared__ unsigned short Ps [4][16][72]; // per-wave P [q][kv], +8 pad

    int tid  = threadIdx.x;
    int w    = tid >> 6, lane = tid & 63;
    int lm   = lane & 15, quad = lane >> 4;
    int blk = blockIdx.x;
    int bh  = blk & 31;          // same bh -> same XCD (dispatch % 8 heuristic)
    int qt  = blk >> 5;
    int b   = bh >> 3, h = bh & 7;
    const int rs = 3 * D_;
    const float scale = 0.08838834764831844f;  // 1/sqrt(128)
    size_t qbase  = (size_t)b * S_ * rs + (size_t)h * HD_;
    size_t kbase  = qbase + D_;
    size_t vtbase = ((size_t)b * H_ + h) * (size_t)HD_ * S_;
    int q0 = qt * 64 + w * 16;

    // Q A-frags, pre-scaled by 1/sqrt(hd)
    bf16x8 qf[4];
    #pragma unroll
    for (int kc = 0; kc < 4; ++kc) {
        bf16x8 raw = *(const bf16x8*)(
            qkv + qbase + (size_t)(q0 + lm) * rs + kc * 32 + quad * 8);
        bf16x8 sc;
        #pragma unroll
        for (int j = 0; j < 8; ++j) {
            unsigned short u;
            __builtin_memcpy(&u, (const char*)&raw + 2 * j, 2);
            u = f2bf(bf2f(u) * scale);
            __builtin_memcpy((char*)&sc + 2 * j, &u, 2);
        }
        qf[kc] = sc;
    }

    f32x4 oacc[8];
    #pragma unroll
    for (int n = 0; n < 8; ++n)
        oacc[n] = (f32x4){0.f, 0.f, 0.f, 0.f};
    float lst[4] = {0.f, 0.f, 0.f, 0.f};

    for (int kt = 0; kt < S_ / 64; ++kt) {
        int k0 = kt * 64;
        __syncthreads();
        #pragma unroll
        for (int i = 0; i < 4; ++i) {
            int chunk = tid + 256 * i;
            int r = chunk >> 4, cc = chunk & 15;
            bf16x8 kv8 = *(const bf16x8*)(
                qkv + kbase + (size_t)(k0 + r) * rs + cc * 8);
            *(bf16x8*)&Ks[r][cc * 8] = kv8;
        }
        #pragma unroll
        for (int i = 0; i < 4; ++i) {
            int chunk = tid + 256 * i;
            int d = chunk >> 3, cc = chunk & 7;
            bf16x8 vv8 = *(const bf16x8*)(
                vt + vtbase + (size_t)d * S_ + k0 + cc * 8);
            *(bf16x8*)&Vts[d][cc * 8] = vv8;
        }
        __syncthreads();

        // ---- S = (Q*scale) K^T ----  (16 MFMA)
        f32x4 sacc[4];
        #pragma unroll
        for (int n = 0; n < 4; ++n)
            sacc[n] = (f32x4){0.f, 0.f, 0.f, 0.f};
        #pragma unroll
        for (int n = 0; n < 4; ++n) {
            #pragma unroll
            for (int kc = 0; kc < 4; ++kc) {
                bf16x8 bk = *(const bf16x8*)&Ks[n * 16 + lm][kc * 32 + quad * 8];
                sacc[n] = __builtin_amdgcn_mfma_f32_16x16x32_bf16(
                    qf[kc], bk, sacc[n], 0, 0, 0);
            }
        }

        // ---- fixed-max softmax: P = exp(s), l += row-sum (regs only) ----
        #pragma unroll
        for (int r = 0; r < 4; ++r) {
            float p0 = __expf(sacc[0][r]);
            float p1 = __expf(sacc[1][r]);
            float p2 = __expf(sacc[2][r]);
            float p3 = __expf(sacc[3][r]);
            lst[r] += (p0 + p1) + (p2 + p3);
            int row = quad * 4 + r;
            Ps[w][row][ 0 + lm] = f2bf(p0);
            Ps[w][row][16 + lm] = f2bf(p1);
            Ps[w][row][32 + lm] = f2bf(p2);
            Ps[w][row][48 + lm] = f2bf(p3);
        }

        // ---- O += P V ----  (16 MFMA)
        bf16x8 pa[2];
        #pragma unroll
        for (int kc = 0; kc < 2; ++kc)
            pa[kc] = *(const bf16x8*)&Ps[w][lm][kc * 32 + quad * 8];
        #pragma unroll
        for (int n = 0; n < 8; ++n) {
            bf16x8 bv0 = *(const bf16x8*)&Vts[n * 16 + lm][quad * 8];
            bf16x8 bv1 = *(const bf16x8*)&Vts[n * 16 + lm][32 + quad * 8];
            oacc[n] = __builtin_amdgcn_mfma_f32_16x16x32_bf16(
                pa[0], bv0, oacc[n], 0, 0, 0);
            oacc[n] = __builtin_amdgcn_mfma_f32_16x16x32_bf16(
                pa[1], bv1, oacc[n], 0, 0, 0);
        }
    }

    // one cross-lane l-reduce at the end (16-lane groups share a row)
    float linv[4];
    #pragma unroll
    for (int r = 0; r < 4; ++r) {
        float l = lst[r];
        l += __shfl_xor(l, 1);
        l += __shfl_xor(l, 2);
        l += __shfl_xor(l, 4);
        l += __shfl_xor(l, 8);
        linv[r] = 1.0f / l;
    }
    size_t rowbase = (size_t)b * S_ + (size_t)qt * 64 + w * 16;
    #pragma unroll
    for (int r = 0; r < 4; ++r) {
        size_t row = rowbase + quad * 4 + r;
        unsigned short* dst = ctx + row * D_ + h * HD_ + lm;
        #pragma unroll
        for (int n = 0; n < 8; ++n)
            dst[n * 16] = f2bf(oacc[n][r] * linv[r]);
    }
}

// ---------------------------------------------------------------------------
extern "C" void kernel_launch(void* const* d_in, const int* in_sizes, int n_in,
                              void* d_out, int out_size, void* d_ws, size_t ws_size,
                              hipStream_t stream) {
    (void)in_sizes; (void)n_in; (void)out_size; (void)ws_size;
    const float* x          = (const float*)d_in[0];
    const int*   ts         = (const int*)  d_in[1];
    const float* gamma      = (const float*)d_in[2];
    const float* beta       = (const float*)d_in[3];
    const float* decay      = (const float*)d_in[4];
    const float* shift_W    = (const float*)d_in[5];
    const float* shift_b    = (const float*)d_in[6];
    const float* in_proj_W  = (const float*)d_in[7];
    const float* in_proj_b  = (const float*)d_in[8];
    const float* out_proj_W = (const float*)d_in[9];
    const float* out_proj_b = (const float*)d_in[10];
    float* out = (float*)d_out;

    // ws (90 MiB, all bf16/ushort):
    //   xln[M*D] | qkv[M*3D] | xsb[M*D] (later vt) | wsh | wip | wop
    unsigned short* p     = (unsigned short*)d_ws;
    unsigned short* xln_b = p;
    unsigned short* qkv_b = xln_b + (size_t)M_ * D_;
    unsigned short* xs_b  = qkv_b + (size_t)M_ * 3 * D_;
    unsigned short* wsh_b = xs_b  + (size_t)M_ * D_;
    unsigned short* wip_b = wsh_b + (size_t)D_ * D_;
    unsigned short* wop_b = wip_b + (size_t)3 * D_ * D_;
    unsigned short* vt_b  = xs_b;    // xs_b dead after qkv GEMM
    unsigned short* ctx_b = xln_b;   // xln dead after shift GEMM
    float* xs = out;                 // fp32 shift output lives in d_out

    f2bf_kernel<<<D_ * D_ / 1024,     256, 0, stream>>>(shift_W,    wsh_b);
    f2bf_kernel<<<3 * D_ * D_ / 1024, 256, 0, stream>>>(in_proj_W,  wip_b);
    f2bf_kernel<<<D_ * D_ / 1024,     256, 0, stream>>>(out_proj_W, wop_b);

    ln_kernel<<<M_, 256, 0, stream>>>(x, ts, gamma, beta, decay, xln_b);

    gemm_mfma<<<dim3(D_ / 128, M_ / 128), 256, 0, stream>>>(
        xln_b, wsh_b, shift_b, nullptr, xln_b, xs, xs_b, M_, D_, D_);
    gemm_mfma<<<dim3(3 * D_ / 128, M_ / 128), 256, 0, stream>>>(
        xs_b, wip_b, in_proj_b, nullptr, nullptr, nullptr, qkv_b, M_, 3 * D_, D_);

    transpose_v<<<dim3(S_ / 64, D_ / 64, B_), 256, 0, stream>>>(qkv_b, vt_b);
    flash_mfma<<<dim3((S_ / 64) * H_ * B_), 256, 0, stream>>>(qkv_b, vt_b, ctx_b);

    gemm_mfma<<<dim3(D_ / 128, M_ / 128), 256, 0, stream>>>(
        ctx_b, wop_b, out_proj_b, xs, nullptr, out, nullptr, M_, D_, D_);
}